// Round 9
// baseline (155.188 us; speedup 1.0000x reference)
//
#include <hip/hip_runtime.h>
#include <math.h>

#define DIMX 128
#define HIDX 256
#define NBX 2048
#define NTOTX 32768
#define NMAXX 32
#define VMID 192
#define SMID 128
#define DMID 192

#define EROWS 32
#define SP 34         // [k][r] pitch: float2-aligned; GEMM reads wave-uniform broadcast
#define NSEGMAX 128   // segment-size cap (multinomial mean 16, P(n>60) ~ 1e-16)

__device__ __forceinline__ float mishf(float v) {
    // exact identity: tanh(log1p(e^v)) = (u^2+2u)/(u^2+2u+2), u=e^v
    if (v > 20.0f) return v;          // tanh(softplus(v)) == 1.0f in fp32
    float u = expf(v);
    float t = u * (u + 2.0f);
    return v * (t / (t + 2.0f));
}

// one-time weight repack: wI[kg][col][kk] = w[(4kg+kk)][col]  (float4 per (kg,col))
__global__ void k_wt(const float* __restrict__ w1, const float* __restrict__ w2,
                     float* __restrict__ wI1, float* __restrict__ wI2) {
    int i = blockIdx.x * blockDim.x + threadIdx.x;
    if (i < DIMX * VMID) {
        int k = i / VMID, c = i % VMID;
        wI1[((k >> 2) * VMID + c) * 4 + (k & 3)] = w1[i];
    }
    int i2 = i - DIMX * VMID;
    if (i2 >= 0 && i2 < VMID * HIDX) {
        int k = i2 / HIDX, c = i2 % HIDX;
        wI2[((k >> 2) * HIDX + c) * 4 + (k & 3)] = w2[i2];
    }
}

// fused encoder + mag: lane=column, 8 rows/thread; weights via coalesced
// float4 (4 k-steps per load) from repacked wI1/wI2; x^T broadcast from LDS.
__global__ __launch_bounds__(256, 4) void k_enc(const float* __restrict__ x,
    const float* __restrict__ rw, const float* __restrict__ rb,
    const float4* __restrict__ wI1, const float* __restrict__ b1,
    const float* __restrict__ g1, const float* __restrict__ be1,
    const float4* __restrict__ wI2, const float* __restrict__ b2,
    float* __restrict__ h, float* __restrict__ mag) {
    __shared__ __align__(16) float sT[VMID * SP];  // xT[128][34] then actT[192][34]
    int tid = threadIdx.x;
    int rowbase = blockIdx.x * EROWS;

    // stage x^T: coalesced float4 reads
#pragma unroll
    for (int it = 0; it < 4; it++) {
        int idx = it * 256 + tid;
        int r = idx >> 5, kq = idx & 31;
        float4 v = ((const float4*)x)[(size_t)(rowbase + r) * 32 + kq];
        sT[(4 * kq + 0) * SP + r] = v.x;
        sT[(4 * kq + 1) * SP + r] = v.y;
        sT[(4 * kq + 2) * SP + r] = v.z;
        sT[(4 * kq + 3) * SP + r] = v.w;
    }
    __syncthreads();

    // mag = x . rank_w (one wave-half; xT read-only here)
    if (tid < EROWS) {
        float s = 0.0f;
        for (int k = 0; k < DIMX; k++) s += sT[k * SP + tid] * rw[k];
        mag[rowbase + tid] = s + rb[0];
    }

    int c = tid & 63;      // col base (lane)
    int rg = tid >> 6;     // row group of 8 (wave-uniform)
    int r0 = rg * 8;

    // ---- GEMM1: per 4-k group: 3 coalesced f4 weight loads, 96 FMA ----
    float a0[8], a1[8], a2[8];
#pragma unroll
    for (int i = 0; i < 8; i++) { a0[i] = 0.f; a1[i] = 0.f; a2[i] = 0.f; }
    const float4* w1g = wI1 + c;
#pragma unroll 2
    for (int kg = 0; kg < DIMX / 4; kg++) {
        float4 wa = w1g[kg * VMID];
        float4 wb = w1g[kg * VMID + 64];
        float4 wc = w1g[kg * VMID + 128];
        const float waA[4] = {wa.x, wa.y, wa.z, wa.w};
        const float wbA[4] = {wb.x, wb.y, wb.z, wb.w};
        const float wcA[4] = {wc.x, wc.y, wc.z, wc.w};
#pragma unroll
        for (int kk = 0; kk < 4; kk++) {
            const float2* xp = (const float2*)&sT[(4 * kg + kk) * SP + r0];
            float2 t0 = xp[0], t1 = xp[1], t2 = xp[2], t3 = xp[3];
            float xv[8] = {t0.x, t0.y, t1.x, t1.y, t2.x, t2.y, t3.x, t3.y};
#pragma unroll
            for (int i = 0; i < 8; i++) {
                a0[i] += waA[kk] * xv[i];
                a1[i] += wbA[kk] * xv[i];
                a2[i] += wcA[kk] * xv[i];
            }
        }
    }

    // ---- LayerNorm + mish (registers + shuffles only) ----
    float b1a = b1[c], b1b = b1[c + 64], b1c = b1[c + 128];
    float g1a = g1[c], g1b = g1[c + 64], g1c = g1[c + 128];
    float e1a = be1[c], e1b = be1[c + 64], e1c = be1[c + 128];
#pragma unroll
    for (int i = 0; i < 8; i++) {
        float v0 = a0[i] + b1a, v1 = a1[i] + b1b, v2 = a2[i] + b1c;
        float s = v0 + v1 + v2;
#pragma unroll
        for (int off = 32; off; off >>= 1) s += __shfl_xor(s, off, 64);
        float mean = s / 192.0f;
        float d0 = v0 - mean, d1 = v1 - mean, d2 = v2 - mean;
        float q = d0 * d0 + d1 * d1 + d2 * d2;
#pragma unroll
        for (int off = 32; off; off >>= 1) q += __shfl_xor(q, off, 64);
        float inv = 1.0f / sqrtf(q / 192.0f + 1e-5f);
        a0[i] = mishf(d0 * inv * g1a + e1a);
        a1[i] = mishf(d1 * inv * g1b + e1b);
        a2[i] = mishf(d2 * inv * g1c + e1c);
    }
    __syncthreads();   // all GEMM1 LDS reads done before overwrite
#pragma unroll
    for (int i = 0; i < 8; i++) {
        sT[c * SP + r0 + i]          = a0[i];
        sT[(c + 64) * SP + r0 + i]   = a1[i];
        sT[(c + 128) * SP + r0 + i]  = a2[i];
    }
    __syncthreads();

    // ---- GEMM2: per 4-k group: 4 coalesced f4 weight loads, 128 FMA ----
    float c0[8], c1[8], c2[8], c3[8];
#pragma unroll
    for (int i = 0; i < 8; i++) { c0[i] = 0.f; c1[i] = 0.f; c2[i] = 0.f; c3[i] = 0.f; }
    const float4* w2g = wI2 + c;
#pragma unroll 2
    for (int kg = 0; kg < VMID / 4; kg++) {
        float4 wa = w2g[kg * HIDX];
        float4 wb = w2g[kg * HIDX + 64];
        float4 wc = w2g[kg * HIDX + 128];
        float4 wd = w2g[kg * HIDX + 192];
        const float waA[4] = {wa.x, wa.y, wa.z, wa.w};
        const float wbA[4] = {wb.x, wb.y, wb.z, wb.w};
        const float wcA[4] = {wc.x, wc.y, wc.z, wc.w};
        const float wdA[4] = {wd.x, wd.y, wd.z, wd.w};
#pragma unroll
        for (int kk = 0; kk < 4; kk++) {
            const float2* ap = (const float2*)&sT[(4 * kg + kk) * SP + r0];
            float2 t0 = ap[0], t1 = ap[1], t2 = ap[2], t3 = ap[3];
            float av[8] = {t0.x, t0.y, t1.x, t1.y, t2.x, t2.y, t3.x, t3.y};
#pragma unroll
            for (int i = 0; i < 8; i++) {
                c0[i] += waA[kk] * av[i];
                c1[i] += wbA[kk] * av[i];
                c2[i] += wcA[kk] * av[i];
                c3[i] += wdA[kk] * av[i];
            }
        }
    }
    float b2a = b2[c], b2b = b2[c + 64], b2c = b2[c + 128], b2d = b2[c + 192];
#pragma unroll
    for (int i = 0; i < 8; i++) {
        size_t row = (size_t)(rowbase + r0 + i);
        h[row * HIDX + c]        = c0[i] + b2a;
        h[row * HIDX + c + 64]   = c1[i] + b2b;
        h[row * HIDX + c + 128]  = c2[i] + b2c;
        h[row * HIDX + c + 192]  = c3[i] + b2d;
    }
}

// seg-bounds + in-LDS rank + z segment sum (inline sincos); writes zre/zim
__global__ __launch_bounds__(256) void k_z(const float* __restrict__ h,
    const int* __restrict__ batch, const float* __restrict__ mag,
    const float* __restrict__ cw, const float* __restrict__ cb,
    float* __restrict__ zre, float* __restrict__ zim) {
    __shared__ float magL[NSEGMAX];
    __shared__ int   ordL[NSEGMAX];
    __shared__ int   shs, shn;
    int b = blockIdx.x, j = threadIdx.x;
    if (j == 0) {
        int lo = 0, hi = NTOTX;
        while (lo < hi) { int m = (lo + hi) >> 1; if (batch[m] < b) lo = m + 1; else hi = m; }
        int stt = lo;
        hi = NTOTX;
        while (lo < hi) { int m = (lo + hi) >> 1; if (batch[m] <= b) lo = m + 1; else hi = m; }
        shs = stt; shn = lo - stt;
    }
    __syncthreads();
    int s = shs, n_true = shn;
    int n = (n_true < NSEGMAX) ? n_true : NSEGMAX;
    if (j < n) magL[j] = mag[s + j];
    __syncthreads();
    if (j < n) {                          // stable rank within segment (lexsort tie: idx)
        float mi = magL[j];
        int rk = 0;
        for (int q = 0; q < n; q++) {
            float mq = magL[q];
            rk += (mq < mi) || (mq == mi && q < j);
        }
        ordL[rk] = s + j;
    }
    __syncthreads();

    float t = (float)j * (1.0f / 255.0f);
    float zr = 0.f, zi = 0.f;
    int p = 0;
    for (; p + 1 < n; p += 2) {           // accumulation ORDER = p ascending (fp32-exact)
        int e0 = ordL[p], e1 = ordL[p + 1];
        float hv0 = h[(size_t)e0 * HIDX + j];
        float hv1 = h[(size_t)e1 * HIDX + j];
        float sv0, cv0, sv1, cv1;
        sincosf((t * (float)p) * 8.0f, &sv0, &cv0);
        sincosf((t * (float)(p + 1)) * 8.0f, &sv1, &cv1);
        zr += hv0 * cv0; zi += hv0 * sv0;
        zr += hv1 * cv1; zi += hv1 * sv1;
    }
    if (p < n) {
        int e = ordL[p];
        float hv = h[(size_t)e * HIDX + j];
        float sv, cv;
        sincosf((t * (float)p) * 8.0f, &sv, &cv);
        zr += hv * cv; zi += hv * sv;
    }
    float nf = (float)n_true;
    zre[(size_t)b * HIDX + j] = zr + nf * cw[j] + cb[j];
    zim[(size_t)b * HIDX + j] = zi;
}

// size MLP, 8 batches/block: sw1 stream amortized 8x.
__global__ __launch_bounds__(256) void k_size(const float* __restrict__ zre,
    const float* __restrict__ cw, const float* __restrict__ cb,
    const float* __restrict__ sw1, const float* __restrict__ sb1,
    const float* __restrict__ sg, const float* __restrict__ sbe,
    const float* __restrict__ sw2, const float* __restrict__ sb2,
    float* __restrict__ zcre, float* __restrict__ out_mask,
    float* __restrict__ out_np, int* __restrict__ npredi) {
    __shared__ float zs[8][HIDX];          // 8 KB
    __shared__ float rA[16], rB[16], rC[16];
    __shared__ float snpf[8];
    int tid = threadIdx.x;
    int b0 = blockIdx.x * 8;
#pragma unroll
    for (int it = 0; it < 8; it++) {
        int idx = it * 256 + tid;
        zs[idx >> 8][idx & 255] = zre[(size_t)(b0 + (idx >> 8)) * HIDX + (idx & 255)];
    }
    __syncthreads();

    int g = tid >> 7;          // batch-half: batches b0+4g .. b0+4g+3
    int j = tid & 127;
    int wv = (tid >> 6) & 1;   // wave within group
    float acc[4];
    float vb1 = sb1[j];
#pragma unroll
    for (int q = 0; q < 4; q++) acc[q] = vb1;
    for (int k = 0; k < HIDX; k++) {
        float w = sw1[k * SMID + j];
#pragma unroll
        for (int q = 0; q < 4; q++) acc[q] += zs[g * 4 + q][k] * w;
    }
#pragma unroll
    for (int q = 0; q < 4; q++) {
        float sa = acc[q];
#pragma unroll
        for (int off = 32; off; off >>= 1) sa += __shfl_xor(sa, off, 64);
        if ((tid & 63) == 0) rA[(g * 2 + wv) * 4 + q] = sa;
    }
    __syncthreads();
    float d[4];
#pragma unroll
    for (int q = 0; q < 4; q++) {
        float mean = (rA[(g * 2) * 4 + q] + rA[(g * 2 + 1) * 4 + q]) / 128.0f;
        d[q] = acc[q] - mean;
        float qq = d[q] * d[q];
#pragma unroll
        for (int off = 32; off; off >>= 1) qq += __shfl_xor(qq, off, 64);
        if ((tid & 63) == 0) rB[(g * 2 + wv) * 4 + q] = qq;
    }
    __syncthreads();
    float gj = sg[j], bej = sbe[j], w2j = sw2[j];
#pragma unroll
    for (int q = 0; q < 4; q++) {
        float var = (rB[(g * 2) * 4 + q] + rB[(g * 2 + 1) * 4 + q]) / 128.0f;
        float lv = d[q] * (1.0f / sqrtf(var + 1e-5f)) * gj + bej;
        float p2 = mishf(lv) * w2j;
#pragma unroll
        for (int off = 32; off; off >>= 1) p2 += __shfl_xor(p2, off, 64);
        if ((tid & 63) == 0) rC[(g * 2 + wv) * 4 + q] = p2;
    }
    __syncthreads();
    if (tid < 8) {
        int q = tid & 3, gg = tid >> 2;
        float h2 = rC[(gg * 2) * 4 + q] + rC[(gg * 2 + 1) * 4 + q] + sb2[0];
        float npf = fmaxf(rintf(h2), 0.0f);   // rintf == round-half-even == jnp.round
        int npi = min((int)npf, NMAXX);
        snpf[tid] = npf;
        out_np[b0 + tid] = (float)npi;
        npredi[b0 + tid] = npi;
    }
    __syncthreads();
#pragma unroll
    for (int it = 0; it < 8; it++) {
        int idx = it * 256 + tid;
        int bi = idx >> 8, jj = idx & 255;
        zcre[(size_t)(b0 + bi) * HIDX + jj] = zs[bi][jj] - (snpf[bi] * cw[jj] + cb[jj]);
    }
    {   // mask: 8 batches x 32
        int bi = tid >> 5, m = tid & 31;
        out_mask[(b0 + bi) * NMAXX + m] = (m < ((int)fminf(snpf[bi], 32.0f))) ? 1.0f : 0.0f;
    }
}

// decoder: per-(m,b) blocks; masked rows write zeros; inline sincos keys
__global__ __launch_bounds__(256) void k_dec(const float* __restrict__ zcre,
    const float* __restrict__ zim, const int* __restrict__ npredi,
    const float* __restrict__ w1, const float* __restrict__ b1,
    const float* __restrict__ w2, const float* __restrict__ b2,
    float* __restrict__ xr) {
    int m = blockIdx.x, b = blockIdx.y;
    int tid = threadIdx.x;
    size_t row = (size_t)b * NMAXX + m;
    if (m >= npredi[b]) {
        if (tid < DIMX) xr[row * DIMX + tid] = 0.0f;
        return;
    }
    __shared__ float zp[HIDX];
    __shared__ float a[DMID];
    {
        float t = (float)tid * (1.0f / 255.0f);
        float sv, cv;
        sincosf((t * (float)m) * 8.0f, &sv, &cv);
        zp[tid] = zcre[(size_t)b * HIDX + tid] * cv - zim[(size_t)b * HIDX + tid] * sv;
    }
    __syncthreads();
    if (tid < DMID) {
        float v = b1[tid];
#pragma unroll 4
        for (int k = 0; k < HIDX; k++) v += zp[k] * w1[k * DMID + tid];
        a[tid] = mishf(v);
    }
    __syncthreads();
    if (tid < DIMX) {
        float v = b2[tid];
#pragma unroll 4
        for (int k = 0; k < DMID; k++) v += a[k] * w2[k * DIMX + tid];
        xr[row * DIMX + tid] = v;
    }
}

extern "C" void kernel_launch(void* const* d_in, const int* in_sizes, int n_in,
                              void* d_out, int out_size, void* d_ws, size_t ws_size,
                              hipStream_t stream) {
    const float* x      = (const float*)d_in[0];
    const int*   batch  = (const int*)d_in[1];
    const float* rank_w = (const float*)d_in[2];
    const float* rank_b = (const float*)d_in[3];
    const float* vw1    = (const float*)d_in[4];
    const float* vb1    = (const float*)d_in[5];
    const float* vlg    = (const float*)d_in[6];
    const float* vlb    = (const float*)d_in[7];
    const float* vw2    = (const float*)d_in[8];
    const float* vb2    = (const float*)d_in[9];
    const float* cw     = (const float*)d_in[10];
    const float* cb     = (const float*)d_in[11];
    const float* sw1    = (const float*)d_in[12];
    const float* sb1    = (const float*)d_in[13];
    const float* slg    = (const float*)d_in[14];
    const float* slb    = (const float*)d_in[15];
    const float* sw2    = (const float*)d_in[16];
    const float* sb2    = (const float*)d_in[17];
    const float* dw1    = (const float*)d_in[18];
    const float* db1    = (const float*)d_in[19];
    const float* dw2    = (const float*)d_in[20];
    const float* db2    = (const float*)d_in[21];

    char* ws = (char*)d_ws;
    size_t off = 0;
    auto alloc = [&](size_t bytes) {
        void* p = ws + off;
        off += (bytes + 255) & ~(size_t)255;
        return p;
    };
    float* mag  = (float*)alloc((size_t)NTOTX * 4);
    float* zre  = (float*)alloc((size_t)NBX * HIDX * 4);
    float* zim  = (float*)alloc((size_t)NBX * HIDX * 4);
    float* zcre = (float*)alloc((size_t)NBX * HIDX * 4);
    int*   npi  = (int*)alloc((size_t)NBX * 4);
    float* wI1  = (float*)alloc((size_t)DIMX * VMID * 4);
    float* wI2  = (float*)alloc((size_t)VMID * HIDX * 4);
    float* h    = (float*)alloc((size_t)NTOTX * HIDX * 4);

    float* out_xr   = (float*)d_out;
    float* out_mask = out_xr + (size_t)NBX * NMAXX * DIMX;
    float* out_np   = out_mask + (size_t)NBX * NMAXX;

    hipLaunchKernelGGL(k_wt,   dim3((DIMX * VMID + VMID * HIDX + 255) / 256), dim3(256), 0, stream,
                       vw1, vw2, wI1, wI2);
    hipLaunchKernelGGL(k_enc,  dim3(NTOTX / EROWS), dim3(256), 0, stream,
                       x, rank_w, rank_b, (const float4*)wI1, vb1, vlg, vlb,
                       (const float4*)wI2, vb2, h, mag);
    hipLaunchKernelGGL(k_z,    dim3(NBX), dim3(HIDX), 0, stream,
                       h, batch, mag, cw, cb, zre, zim);
    hipLaunchKernelGGL(k_size, dim3(NBX / 8), dim3(256), 0, stream,
                       zre, cw, cb, sw1, sb1, slg, slb, sw2, sb2,
                       zcre, out_mask, out_np, npi);
    hipLaunchKernelGGL(k_dec,  dim3(NMAXX, NBX), dim3(256), 0, stream,
                       zcre, zim, npi, dw1, db1, dw2, db2, out_xr);
    (void)in_sizes; (void)n_in; (void)out_size; (void)ws_size;
}

// Round 10
// 152.693 us; speedup vs baseline: 1.0163x; 1.0163x over previous
//
#include <hip/hip_runtime.h>
#include <math.h>

#define DIMX 128
#define HIDX 256
#define NBX 2048
#define NTOTX 32768
#define NMAXX 32
#define VMID 192
#define SMID 128
#define DMID 192

#define EROWS 64
#define SP 66         // [k][r] pitch (floats): float2-aligned; GEMM reads are broadcast
#define NSEGMAX 128   // segment-size cap (multinomial mean 16, P(n>60) ~ 1e-16)

__device__ __forceinline__ float mishf(float v) {
    // exact identity: tanh(log1p(e^v)) = (u^2+2u)/(u^2+2u+2), u=e^v
    if (v > 20.0f) return v;          // tanh(softplus(v)) == 1.0f in fp32
    float u = expf(v);
    float t = u * (u + 2.0f);
    return v * (t / (t + 2.0f));
}

// one-time weight repack: wI[kg][col][kk] = w[(4kg+kk)][col]  (float4 per (kg,col))
__global__ void k_wt(const float* __restrict__ w1, const float* __restrict__ w2,
                     float* __restrict__ wI1, float* __restrict__ wI2) {
    int i = blockIdx.x * blockDim.x + threadIdx.x;
    if (i < DIMX * VMID) {
        int k = i / VMID, c = i % VMID;
        wI1[((k >> 2) * VMID + c) * 4 + (k & 3)] = w1[i];
    }
    int i2 = i - DIMX * VMID;
    if (i2 >= 0 && i2 < VMID * HIDX) {
        int k = i2 / HIDX, c = i2 % HIDX;
        wI2[((k >> 2) * HIDX + c) * 4 + (k & 3)] = w2[i2];
    }
}

// fused encoder + mag: lane=column, 8 rows/thread, 64 rows/block (8 waves).
// Weights: coalesced float4 (4 k-steps per load) from repacked wI1/wI2;
// x^T broadcast from LDS (wave-uniform addresses).
__global__ __launch_bounds__(512, 4) void k_enc(const float* __restrict__ x,
    const float* __restrict__ rw, const float* __restrict__ rb,
    const float4* __restrict__ wI1, const float* __restrict__ b1,
    const float* __restrict__ g1, const float* __restrict__ be1,
    const float4* __restrict__ wI2, const float* __restrict__ b2,
    float* __restrict__ h, float* __restrict__ mag) {
    __shared__ __align__(16) float sT[VMID * SP];  // xT[128][66] then actT[192][66]
    int tid = threadIdx.x;
    int rowbase = blockIdx.x * EROWS;

    // stage x^T: coalesced float4 reads
#pragma unroll
    for (int it = 0; it < 4; it++) {
        int idx = it * 512 + tid;
        int r = idx >> 5, kq = idx & 31;
        float4 v = ((const float4*)x)[(size_t)(rowbase + r) * 32 + kq];
        sT[(4 * kq + 0) * SP + r] = v.x;
        sT[(4 * kq + 1) * SP + r] = v.y;
        sT[(4 * kq + 2) * SP + r] = v.z;
        sT[(4 * kq + 3) * SP + r] = v.w;
    }
    __syncthreads();

    // mag = x . rank_w (wave 0; xT read-only here)
    if (tid < EROWS) {
        float s = 0.0f;
        for (int k = 0; k < DIMX; k++) s += sT[k * SP + tid] * rw[k];
        mag[rowbase + tid] = s + rb[0];
    }

    int c = tid & 63;      // col base (lane)
    int rg = tid >> 6;     // row group of 8 (wave-uniform)
    int r0 = rg * 8;

    // ---- GEMM1: per 4-k group: 3 coalesced f4 weight loads, 96 FMA ----
    float a0[8], a1[8], a2[8];
#pragma unroll
    for (int i = 0; i < 8; i++) { a0[i] = 0.f; a1[i] = 0.f; a2[i] = 0.f; }
    const float4* w1g = wI1 + c;
#pragma unroll 4
    for (int kg = 0; kg < DIMX / 4; kg++) {
        float4 wa = w1g[kg * VMID];
        float4 wb = w1g[kg * VMID + 64];
        float4 wc = w1g[kg * VMID + 128];
        const float waA[4] = {wa.x, wa.y, wa.z, wa.w};
        const float wbA[4] = {wb.x, wb.y, wb.z, wb.w};
        const float wcA[4] = {wc.x, wc.y, wc.z, wc.w};
#pragma unroll
        for (int kk = 0; kk < 4; kk++) {
            const float2* xp = (const float2*)&sT[(4 * kg + kk) * SP + r0];
            float2 t0 = xp[0], t1 = xp[1], t2 = xp[2], t3 = xp[3];
            float xv[8] = {t0.x, t0.y, t1.x, t1.y, t2.x, t2.y, t3.x, t3.y};
#pragma unroll
            for (int i = 0; i < 8; i++) {
                a0[i] += waA[kk] * xv[i];
                a1[i] += wbA[kk] * xv[i];
                a2[i] += wcA[kk] * xv[i];
            }
        }
    }

    // ---- LayerNorm + mish (registers + shuffles only) ----
    float b1a = b1[c], b1b = b1[c + 64], b1c = b1[c + 128];
    float g1a = g1[c], g1b = g1[c + 64], g1c = g1[c + 128];
    float e1a = be1[c], e1b = be1[c + 64], e1c = be1[c + 128];
#pragma unroll
    for (int i = 0; i < 8; i++) {
        float v0 = a0[i] + b1a, v1 = a1[i] + b1b, v2 = a2[i] + b1c;
        float s = v0 + v1 + v2;
#pragma unroll
        for (int off = 32; off; off >>= 1) s += __shfl_xor(s, off, 64);
        float mean = s / 192.0f;
        float d0 = v0 - mean, d1 = v1 - mean, d2 = v2 - mean;
        float q = d0 * d0 + d1 * d1 + d2 * d2;
#pragma unroll
        for (int off = 32; off; off >>= 1) q += __shfl_xor(q, off, 64);
        float inv = 1.0f / sqrtf(q / 192.0f + 1e-5f);
        a0[i] = mishf(d0 * inv * g1a + e1a);
        a1[i] = mishf(d1 * inv * g1b + e1b);
        a2[i] = mishf(d2 * inv * g1c + e1c);
    }
    __syncthreads();   // all GEMM1 LDS reads done before overwrite
#pragma unroll
    for (int i = 0; i < 8; i++) {
        sT[c * SP + r0 + i]          = a0[i];
        sT[(c + 64) * SP + r0 + i]   = a1[i];
        sT[(c + 128) * SP + r0 + i]  = a2[i];
    }
    __syncthreads();

    // ---- GEMM2: per 4-k group: 4 coalesced f4 weight loads, 128 FMA ----
    float c0[8], c1[8], c2[8], c3[8];
#pragma unroll
    for (int i = 0; i < 8; i++) { c0[i] = 0.f; c1[i] = 0.f; c2[i] = 0.f; c3[i] = 0.f; }
    const float4* w2g = wI2 + c;
#pragma unroll 4
    for (int kg = 0; kg < VMID / 4; kg++) {
        float4 wa = w2g[kg * HIDX];
        float4 wb = w2g[kg * HIDX + 64];
        float4 wc = w2g[kg * HIDX + 128];
        float4 wd = w2g[kg * HIDX + 192];
        const float waA[4] = {wa.x, wa.y, wa.z, wa.w};
        const float wbA[4] = {wb.x, wb.y, wb.z, wb.w};
        const float wcA[4] = {wc.x, wc.y, wc.z, wc.w};
        const float wdA[4] = {wd.x, wd.y, wd.z, wd.w};
#pragma unroll
        for (int kk = 0; kk < 4; kk++) {
            const float2* ap = (const float2*)&sT[(4 * kg + kk) * SP + r0];
            float2 t0 = ap[0], t1 = ap[1], t2 = ap[2], t3 = ap[3];
            float av[8] = {t0.x, t0.y, t1.x, t1.y, t2.x, t2.y, t3.x, t3.y};
#pragma unroll
            for (int i = 0; i < 8; i++) {
                c0[i] += waA[kk] * av[i];
                c1[i] += wbA[kk] * av[i];
                c2[i] += wcA[kk] * av[i];
                c3[i] += wdA[kk] * av[i];
            }
        }
    }
    float b2a = b2[c], b2b = b2[c + 64], b2c = b2[c + 128], b2d = b2[c + 192];
#pragma unroll
    for (int i = 0; i < 8; i++) {
        size_t row = (size_t)(rowbase + r0 + i);
        h[row * HIDX + c]        = c0[i] + b2a;
        h[row * HIDX + c + 64]   = c1[i] + b2b;
        h[row * HIDX + c + 128]  = c2[i] + b2c;
        h[row * HIDX + c + 192]  = c3[i] + b2d;
    }
}

// seg-bounds + in-LDS rank + z segment sum (inline sincos); writes zre/zim
__global__ __launch_bounds__(256) void k_z(const float* __restrict__ h,
    const int* __restrict__ batch, const float* __restrict__ mag,
    const float* __restrict__ cw, const float* __restrict__ cb,
    float* __restrict__ zre, float* __restrict__ zim) {
    __shared__ float magL[NSEGMAX];
    __shared__ int   ordL[NSEGMAX];
    __shared__ int   shs, shn;
    int b = blockIdx.x, j = threadIdx.x;
    if (j == 0) {
        int lo = 0, hi = NTOTX;
        while (lo < hi) { int m = (lo + hi) >> 1; if (batch[m] < b) lo = m + 1; else hi = m; }
        int stt = lo;
        hi = NTOTX;
        while (lo < hi) { int m = (lo + hi) >> 1; if (batch[m] <= b) lo = m + 1; else hi = m; }
        shs = stt; shn = lo - stt;
    }
    __syncthreads();
    int s = shs, n_true = shn;
    int n = (n_true < NSEGMAX) ? n_true : NSEGMAX;
    if (j < n) magL[j] = mag[s + j];
    __syncthreads();
    if (j < n) {                          // stable rank within segment (lexsort tie: idx)
        float mi = magL[j];
        int rk = 0;
        for (int q = 0; q < n; q++) {
            float mq = magL[q];
            rk += (mq < mi) || (mq == mi && q < j);
        }
        ordL[rk] = s + j;
    }
    __syncthreads();

    float t = (float)j * (1.0f / 255.0f);
    float zr = 0.f, zi = 0.f;
    int p = 0;
    for (; p + 1 < n; p += 2) {           // accumulation ORDER = p ascending (fp32-exact)
        int e0 = ordL[p], e1 = ordL[p + 1];
        float hv0 = h[(size_t)e0 * HIDX + j];
        float hv1 = h[(size_t)e1 * HIDX + j];
        float sv0, cv0, sv1, cv1;
        sincosf((t * (float)p) * 8.0f, &sv0, &cv0);
        sincosf((t * (float)(p + 1)) * 8.0f, &sv1, &cv1);
        zr += hv0 * cv0; zi += hv0 * sv0;
        zr += hv1 * cv1; zi += hv1 * sv1;
    }
    if (p < n) {
        int e = ordL[p];
        float hv = h[(size_t)e * HIDX + j];
        float sv, cv;
        sincosf((t * (float)p) * 8.0f, &sv, &cv);
        zr += hv * cv; zi += hv * sv;
    }
    float nf = (float)n_true;
    zre[(size_t)b * HIDX + j] = zr + nf * cw[j] + cb[j];
    zim[(size_t)b * HIDX + j] = zi;
}

// size MLP, 8 batches/block: sw1 stream amortized 8x.
__global__ __launch_bounds__(256) void k_size(const float* __restrict__ zre,
    const float* __restrict__ cw, const float* __restrict__ cb,
    const float* __restrict__ sw1, const float* __restrict__ sb1,
    const float* __restrict__ sg, const float* __restrict__ sbe,
    const float* __restrict__ sw2, const float* __restrict__ sb2,
    float* __restrict__ zcre, float* __restrict__ out_mask,
    float* __restrict__ out_np, int* __restrict__ npredi) {
    __shared__ float zs[8][HIDX];          // 8 KB
    __shared__ float rA[16], rB[16], rC[16];
    __shared__ float snpf[8];
    int tid = threadIdx.x;
    int b0 = blockIdx.x * 8;
#pragma unroll
    for (int it = 0; it < 8; it++) {
        int idx = it * 256 + tid;
        zs[idx >> 8][idx & 255] = zre[(size_t)(b0 + (idx >> 8)) * HIDX + (idx & 255)];
    }
    __syncthreads();

    int g = tid >> 7;          // batch-half: batches b0+4g .. b0+4g+3
    int j = tid & 127;
    int wv = (tid >> 6) & 1;   // wave within group
    float acc[4];
    float vb1 = sb1[j];
#pragma unroll
    for (int q = 0; q < 4; q++) acc[q] = vb1;
    for (int k = 0; k < HIDX; k++) {
        float w = sw1[k * SMID + j];
#pragma unroll
        for (int q = 0; q < 4; q++) acc[q] += zs[g * 4 + q][k] * w;
    }
#pragma unroll
    for (int q = 0; q < 4; q++) {
        float sa = acc[q];
#pragma unroll
        for (int off = 32; off; off >>= 1) sa += __shfl_xor(sa, off, 64);
        if ((tid & 63) == 0) rA[(g * 2 + wv) * 4 + q] = sa;
    }
    __syncthreads();
    float d[4];
#pragma unroll
    for (int q = 0; q < 4; q++) {
        float mean = (rA[(g * 2) * 4 + q] + rA[(g * 2 + 1) * 4 + q]) / 128.0f;
        d[q] = acc[q] - mean;
        float qq = d[q] * d[q];
#pragma unroll
        for (int off = 32; off; off >>= 1) qq += __shfl_xor(qq, off, 64);
        if ((tid & 63) == 0) rB[(g * 2 + wv) * 4 + q] = qq;
    }
    __syncthreads();
    float gj = sg[j], bej = sbe[j], w2j = sw2[j];
#pragma unroll
    for (int q = 0; q < 4; q++) {
        float var = (rB[(g * 2) * 4 + q] + rB[(g * 2 + 1) * 4 + q]) / 128.0f;
        float lv = d[q] * (1.0f / sqrtf(var + 1e-5f)) * gj + bej;
        float p2 = mishf(lv) * w2j;
#pragma unroll
        for (int off = 32; off; off >>= 1) p2 += __shfl_xor(p2, off, 64);
        if ((tid & 63) == 0) rC[(g * 2 + wv) * 4 + q] = p2;
    }
    __syncthreads();
    if (tid < 8) {
        int q = tid & 3, gg = tid >> 2;
        float h2 = rC[(gg * 2) * 4 + q] + rC[(gg * 2 + 1) * 4 + q] + sb2[0];
        float npf = fmaxf(rintf(h2), 0.0f);   // rintf == round-half-even == jnp.round
        int npi = min((int)npf, NMAXX);
        snpf[tid] = npf;
        out_np[b0 + tid] = (float)npi;
        npredi[b0 + tid] = npi;
    }
    __syncthreads();
#pragma unroll
    for (int it = 0; it < 8; it++) {
        int idx = it * 256 + tid;
        int bi = idx >> 8, jj = idx & 255;
        zcre[(size_t)(b0 + bi) * HIDX + jj] = zs[bi][jj] - (snpf[bi] * cw[jj] + cb[jj]);
    }
    {   // mask: 8 batches x 32
        int bi = tid >> 5, m = tid & 31;
        out_mask[(b0 + bi) * NMAXX + m] = (m < ((int)fminf(snpf[bi], 32.0f))) ? 1.0f : 0.0f;
    }
}

// decoder: one block per batch; zero tail rows (float4), decode rows m<npi serially
__global__ __launch_bounds__(256) void k_dec(const float* __restrict__ zcre,
    const float* __restrict__ zim, const int* __restrict__ npredi,
    const float* __restrict__ w1, const float* __restrict__ b1,
    const float* __restrict__ w2, const float* __restrict__ b2,
    float* __restrict__ xr) {
    __shared__ float zp[HIDX];
    __shared__ float a[DMID];
    int b = blockIdx.x;
    int tid = threadIdx.x;
    int npi = npredi[b];
    // zero rows npi..31 (each row = 32 float4)
    float4* base = (float4*)(xr + (size_t)b * NMAXX * DIMX);
    for (int idx = npi * 32 + tid; idx < NMAXX * 32; idx += 256)
        base[idx] = make_float4(0.f, 0.f, 0.f, 0.f);
    // decode rows 0..npi-1
    for (int m = 0; m < npi; m++) {
        float t = (float)tid * (1.0f / 255.0f);
        float sv, cv;
        sincosf((t * (float)m) * 8.0f, &sv, &cv);
        zp[tid] = zcre[(size_t)b * HIDX + tid] * cv - zim[(size_t)b * HIDX + tid] * sv;
        __syncthreads();
        if (tid < DMID) {
            float v = b1[tid];
#pragma unroll 4
            for (int k = 0; k < HIDX; k++) v += zp[k] * w1[k * DMID + tid];
            a[tid] = mishf(v);
        }
        __syncthreads();
        if (tid < DIMX) {
            float v = b2[tid];
#pragma unroll 4
            for (int k = 0; k < DMID; k++) v += a[k] * w2[k * DIMX + tid];
            xr[((size_t)b * NMAXX + m) * DIMX + tid] = v;
        }
        __syncthreads();
    }
}

extern "C" void kernel_launch(void* const* d_in, const int* in_sizes, int n_in,
                              void* d_out, int out_size, void* d_ws, size_t ws_size,
                              hipStream_t stream) {
    const float* x      = (const float*)d_in[0];
    const int*   batch  = (const int*)d_in[1];
    const float* rank_w = (const float*)d_in[2];
    const float* rank_b = (const float*)d_in[3];
    const float* vw1    = (const float*)d_in[4];
    const float* vb1    = (const float*)d_in[5];
    const float* vlg    = (const float*)d_in[6];
    const float* vlb    = (const float*)d_in[7];
    const float* vw2    = (const float*)d_in[8];
    const float* vb2    = (const float*)d_in[9];
    const float* cw     = (const float*)d_in[10];
    const float* cb     = (const float*)d_in[11];
    const float* sw1    = (const float*)d_in[12];
    const float* sb1    = (const float*)d_in[13];
    const float* slg    = (const float*)d_in[14];
    const float* slb    = (const float*)d_in[15];
    const float* sw2    = (const float*)d_in[16];
    const float* sb2    = (const float*)d_in[17];
    const float* dw1    = (const float*)d_in[18];
    const float* db1    = (const float*)d_in[19];
    const float* dw2    = (const float*)d_in[20];
    const float* db2    = (const float*)d_in[21];

    char* ws = (char*)d_ws;
    size_t off = 0;
    auto alloc = [&](size_t bytes) {
        void* p = ws + off;
        off += (bytes + 255) & ~(size_t)255;
        return p;
    };
    float* mag  = (float*)alloc((size_t)NTOTX * 4);
    float* zre  = (float*)alloc((size_t)NBX * HIDX * 4);
    float* zim  = (float*)alloc((size_t)NBX * HIDX * 4);
    float* zcre = (float*)alloc((size_t)NBX * HIDX * 4);
    int*   npi  = (int*)alloc((size_t)NBX * 4);
    float* wI1  = (float*)alloc((size_t)DIMX * VMID * 4);
    float* wI2  = (float*)alloc((size_t)VMID * HIDX * 4);
    float* h    = (float*)alloc((size_t)NTOTX * HIDX * 4);

    float* out_xr   = (float*)d_out;
    float* out_mask = out_xr + (size_t)NBX * NMAXX * DIMX;
    float* out_np   = out_mask + (size_t)NBX * NMAXX;

    hipLaunchKernelGGL(k_wt,   dim3((DIMX * VMID + VMID * HIDX + 255) / 256), dim3(256), 0, stream,
                       vw1, vw2, wI1, wI2);
    hipLaunchKernelGGL(k_enc,  dim3(NTOTX / EROWS), dim3(512), 0, stream,
                       x, rank_w, rank_b, (const float4*)wI1, vb1, vlg, vlb,
                       (const float4*)wI2, vb2, h, mag);
    hipLaunchKernelGGL(k_z,    dim3(NBX), dim3(HIDX), 0, stream,
                       h, batch, mag, cw, cb, zre, zim);
    hipLaunchKernelGGL(k_size, dim3(NBX / 8), dim3(256), 0, stream,
                       zre, cw, cb, sw1, sb1, slg, slb, sw2, sb2,
                       zcre, out_mask, out_np, npi);
    hipLaunchKernelGGL(k_dec,  dim3(NBX), dim3(256), 0, stream,
                       zcre, zim, npi, dw1, db1, dw2, db2, out_xr);
    (void)in_sizes; (void)n_in; (void)out_size; (void)ws_size;
}